// Round 9
// baseline (867.820 us; speedup 1.0000x reference)
//
#include <hip/hip_runtime.h>

#define BB 256
#define LL 1024
#define TT 128
#define NTH 256  // 4 waves: wave q = pred quarter, lane l = tags {l, l+64}
#define CH 64    // backward chunk rows staged in LDS
#define TTP 129  // padded row stride for transposed trans (kills bank conflicts)
#define PVP 132  // padded pv row stride (conflict-free writes/reads)

typedef unsigned long long ull;

// LDS-only barrier: does NOT drain vmcnt, so in-flight global loads/stores
// stay outstanding across it.
__device__ __forceinline__ void lds_barrier() {
    asm volatile("s_waitcnt lgkmcnt(0)\n\ts_barrier" ::);
}

// ===================== workspace variant =====================
// LDS-return-path model (r8): a wave-uniform ds_read_b128 still delivers
// 64 lanes x 16B = 1KB through the LDS return bus (~12 cyc). The old 8-wave
// layout issued 64 such reads/step (~770 cyc of LDS pipe) — the dominant
// per-step cost. This layout: 4 waves, wave q reads its 32 state floats
// ONCE (8 x b128) and each lane computes TWO tags (l, l+64) from them:
// 32 reads/step (~384 cyc). VALU per SIMD unchanged (1 wave x 2 tags vs
// 2 waves x 1 tag).
//
// Forward: values-only Viterbi (no argmax bookkeeping). Per step t stores
// the pre-emission max row m_t[j] to workspace. Backward: exact backpointer
// recovery via bit-exact score recompute + ballot first-match (== jnp.argmax
// first-index semantics, even under ties).
struct FwdSmem {
    float state[TT];          // current Viterbi state
    float pv[4 * PVP];        // partial maxes, pv[q*PVP + j]
    unsigned char tags[LL];   // decoded tags staging
};

__global__ __launch_bounds__(NTH)
void viterbi_ws_kernel(const float* __restrict__ x,
                       const int* __restrict__ lengths,
                       const float* __restrict__ trans,
                       int* __restrict__ out,
                       float* __restrict__ ws) {
    __shared__ FwdSmem sm;
    extern __shared__ float dyn[];            // tT[TTP*TT] | bm[CH*TT] | bx[CH*TT]
    float* tT = dyn;                          // tT[c*TTP + i] = trans[i*TT + c]
    float* bm = dyn + TTP * TT;               // staged m-history rows
    float* bx = bm + CH * TT;                 // staged x rows

    const int b   = blockIdx.x;
    const int tid = threadIdx.x;
    const int l   = tid & 63;    // lane
    const int q   = tid >> 6;    // wave id == predecessor quarter [32q, 32q+32)

    int lenb = lengths[b];
    if (lenb < 1) lenb = 1;
    if (lenb > LL) lenb = LL;

    // Register-cache trans for BOTH tags this lane owns:
    // tcA[ii] = trans[32q+ii][l], tcB[ii] = trans[32q+ii][l+64]
    float tcA[32], tcB[32];
    #pragma unroll
    for (int ii = 0; ii < 32; ++ii) {
        tcA[ii] = trans[(q * 32 + ii) * TT + l];
        tcB[ii] = trans[(q * 32 + ii) * TT + l + 64];
    }
    // Pin in VGPRs — forbids any spill/remat of the cache.
    #pragma unroll
    for (int ii = 0; ii < 32; ++ii) {
        asm volatile("" : "+v"(tcA[ii]));
        asm volatile("" : "+v"(tcB[ii]));
    }

    // Transposed trans in LDS for the backward pass — padded stride TTP=129:
    // consecutive lanes hit consecutive banks -> 2-way (free). L2-hot reread.
    {
        const int jj = tid & (TT - 1);
        const int hh = tid >> 7;              // 0..1 -> rows [64hh, 64hh+64)
        #pragma unroll
        for (int ii = 0; ii < 64; ++ii) {
            int r = hh * 64 + ii;
            tT[jj * TTP + r] = trans[r * TT + jj];
        }
    }

    const float* xb  = x  + (size_t)b * LL * TT;
    float*       wsb = ws + (size_t)b * LL * TT;

    // row 0 of history := state_0 = x[0,:]
    if (tid < TT) { float v = xb[tid]; sm.state[tid] = v; wsb[tid] = v; }

    float xv = 0.0f, xn = 0.0f;
    if (tid < TT && lenb > 1) xv = xb[TT + tid];
    lds_barrier();

    // ---------------- forward (values only) ----------------
    for (int t = 1; t < lenb; ++t) {
        if (tid < TT) {
            int tn = (t + 1 < lenb) ? (t + 1) : (lenb - 1);
            xn = xb[tn * TT + tid];           // in flight across barriers
        }
        // scan 32 predecessors once, apply to both owned tags
        const float4* st4 = reinterpret_cast<const float4*>(sm.state + q * 32);
        float a0 = -3.4e38f, a1 = -3.4e38f, a2 = -3.4e38f, a3 = -3.4e38f;
        float b0 = -3.4e38f, b1 = -3.4e38f, b2 = -3.4e38f, b3 = -3.4e38f;
        #pragma unroll
        for (int k = 0; k < 8; ++k) {
            float4 sv = st4[k];               // wave-uniform broadcast b128
            a0 = fmaxf(a0, sv.x + tcA[4 * k + 0]);
            a1 = fmaxf(a1, sv.y + tcA[4 * k + 1]);
            a2 = fmaxf(a2, sv.z + tcA[4 * k + 2]);
            a3 = fmaxf(a3, sv.w + tcA[4 * k + 3]);
            b0 = fmaxf(b0, sv.x + tcB[4 * k + 0]);
            b1 = fmaxf(b1, sv.y + tcB[4 * k + 1]);
            b2 = fmaxf(b2, sv.z + tcB[4 * k + 2]);
            b3 = fmaxf(b3, sv.w + tcB[4 * k + 3]);
        }
        // conflict-free padded writes: bank = (4q + l) % 32, consecutive in l
        sm.pv[q * PVP + l]      = fmaxf(fmaxf(a0, a1), fmaxf(a2, a3));
        sm.pv[q * PVP + 64 + l] = fmaxf(fmaxf(b0, b1), fmaxf(b2, b3));
        lds_barrier();
        if (tid < TT) {
            float bv = fmaxf(fmaxf(sm.pv[tid], sm.pv[PVP + tid]),
                             fmaxf(sm.pv[2 * PVP + tid], sm.pv[3 * PVP + tid]));
            wsb[t * TT + tid] = bv;           // m_t row (pre-emission max)
            sm.state[tid] = bv + xv;
            xv = xn;
        }
        lds_barrier();
    }

    // Drain our m-history stores and make them visible block-wide.
    __syncthreads();

    // ---- last_tag: exact first-index argmax over state (wave 0) ----
    int c = 0; float mv = 0.0f;
    if (tid < 64) {
        float s0 = sm.state[l], s1 = sm.state[l + 64];
        float mm = fmaxf(s0, s1);
        #pragma unroll
        for (int off = 1; off < 64; off <<= 1)
            mm = fmaxf(mm, __shfl_xor(mm, off));
        ull blo = __ballot(s0 == mm);         // lo half: indices 0..63 (first)
        if (blo) c = __ffsll(blo) - 1;
        else     c = 64 + __ffsll(__ballot(s1 == mm)) - 1;
        if (lenb > 1) mv = wsb[(lenb - 1) * TT + c];   // m_{len-1}[c]
    }

    // ---- chunked backward walk (wave 0 walks; all threads stage) ----
    // Semantics (matches reference): tags[t] = c, THEN c = bp_t[c].
    int rhi = lenb - 2;                       // highest source row needed
    while (rhi >= 0) {
        int r0 = rhi - (CH - 1); if (r0 < 0) r0 = 0;
        int nrows = rhi - r0 + 1;
        const float4* wm4 = reinterpret_cast<const float4*>(wsb + r0 * TT);
        const float4* wx4 = reinterpret_cast<const float4*>(xb  + r0 * TT);
        float4* bm4 = reinterpret_cast<float4*>(bm);
        float4* bx4 = reinterpret_cast<float4*>(bx);
        int n4 = nrows * (TT / 4);
        for (int i4 = tid; i4 < n4; i4 += NTH) {
            bm4[i4] = wm4[i4];
            float4 v = wx4[i4];
            // row 0 holds state_0 directly: no emission re-add
            if (r0 == 0 && i4 < TT / 4) { v.x = 0.f; v.y = 0.f; v.z = 0.f; v.w = 0.f; }
            bx4[i4] = v;
        }
        lds_barrier();
        if (tid < 64) {
            for (int tt = r0 + nrows; tt >= r0 + 1; --tt) {
                int row = (tt - 1 - r0) * TT;
                // bit-exact recompute of forward scores:
                // state_{t-1}[i] = m + x (same operands/order as forward)
                float slo = (bm[row + l]      + bx[row + l])      + tT[c * TTP + l];
                float shi = (bm[row + 64 + l] + bx[row + 64 + l]) + tT[c * TTP + 64 + l];
                ull blo = __ballot(slo == mv);
                int nc;
                if (blo) nc = __ffsll(blo) - 1;              // first i in 0..63
                else     nc = 64 + __ffsll(__ballot(shi == mv)) - 1;
                if (l == 0) sm.tags[tt] = (unsigned char)c;  // CURRENT tag at tt
                c = nc;                                      // tag at tt-1
                mv = bm[row + c];             // m_{tt-1}[c] for next step
            }
        }
        lds_barrier();                        // protect bm/bx before reload
        rhi = r0 - 1;
    }
    if (tid == 0) sm.tags[0] = (unsigned char)c;
    lds_barrier();

    int* outb = out + (size_t)b * LL;
    for (int tt = tid; tt < LL; tt += NTH)
        outb[tt] = (tt < lenb) ? (int)sm.tags[tt] : 0;
}

// ===================== fallback (no workspace): round-0 kernel =====================
#define FNTH 512
struct SmallSmem {
    float state[TT];
    float pv[FNTH];
    int   pi[FNTH];
    unsigned char tags[LL];
};

__global__ __launch_bounds__(FNTH)
void viterbi_kernel(const float* __restrict__ x,
                    const int* __restrict__ lengths,
                    const float* __restrict__ trans,
                    int* __restrict__ out) {
    __shared__ SmallSmem sm;
    extern __shared__ unsigned char bp[];   // LL*TT bytes

    const int b   = blockIdx.x;
    const int tid = threadIdx.x;
    const int j   = tid & (TT - 1);
    const int q   = tid >> 7;

    int lenb = lengths[b];
    if (lenb < 1) lenb = 1;
    if (lenb > LL) lenb = LL;

    float tc[32];
    #pragma unroll
    for (int ii = 0; ii < 32; ++ii)
        tc[ii] = trans[(q * 32 + ii) * TT + j];

    const float* xb = x + (size_t)b * LL * TT;
    if (tid < TT) sm.state[tid] = xb[tid];

    float xv_cur = 0.0f, xv_next = 0.0f;
    if (tid < TT && lenb > 1) xv_cur = xb[TT + j];
    lds_barrier();

    for (int t = 1; t < lenb; ++t) {
        if (tid < TT) {
            int tn = (t + 1 < lenb) ? (t + 1) : (lenb - 1);
            xv_next = xb[tn * TT + j];
        }
        float best0 = -3.4e38f, best1 = -3.4e38f, best2 = -3.4e38f, best3 = -3.4e38f;
        int   bi0 = 0, bi1 = 1, bi2 = 2, bi3 = 3;
        const float4* st4 = reinterpret_cast<const float4*>(sm.state + q * 32);
        #pragma unroll
        for (int k = 0; k < 8; ++k) {
            float4 sv = st4[k];
            float s0 = sv.x + tc[4 * k + 0];
            float s1 = sv.y + tc[4 * k + 1];
            float s2 = sv.z + tc[4 * k + 2];
            float s3 = sv.w + tc[4 * k + 3];
            if (s0 > best0) { best0 = s0; bi0 = 4 * k + 0; }
            if (s1 > best1) { best1 = s1; bi1 = 4 * k + 1; }
            if (s2 > best2) { best2 = s2; bi2 = 4 * k + 2; }
            if (s3 > best3) { best3 = s3; bi3 = 4 * k + 3; }
        }
        float bb = best0; int bi = bi0;
        if (best1 > bb || (best1 == bb && bi1 < bi)) { bb = best1; bi = bi1; }
        if (best2 > bb || (best2 == bb && bi2 < bi)) { bb = best2; bi = bi2; }
        if (best3 > bb || (best3 == bb && bi3 < bi)) { bb = best3; bi = bi3; }
        sm.pv[tid] = bb;
        sm.pi[tid] = bi + q * 32;
        lds_barrier();

        if (tid < TT) {
            float bv = sm.pv[j];       int ix = sm.pi[j];
            float v1 = sm.pv[j + 128]; int i1 = sm.pi[j + 128];
            float v2 = sm.pv[j + 256]; int i2 = sm.pi[j + 256];
            float v3 = sm.pv[j + 384]; int i3 = sm.pi[j + 384];
            if (v1 > bv) { bv = v1; ix = i1; }
            if (v2 > bv) { bv = v2; ix = i2; }
            if (v3 > bv) { bv = v3; ix = i3; }
            sm.state[j] = bv + xv_cur;
            bp[t * TT + j] = (unsigned char)ix;
            xv_cur = xv_next;
        }
        lds_barrier();
    }

    if (tid == 0) {
        float bv = sm.state[0]; int ix = 0;
        for (int i = 1; i < TT; ++i) {
            float v = sm.state[i];
            if (v > bv) { bv = v; ix = i; }
        }
        int carry = ix;
        for (int t = lenb - 1; t >= 1; --t) {
            sm.tags[t] = (unsigned char)carry;
            carry = bp[t * TT + carry];
        }
        sm.tags[0] = (unsigned char)carry;
    }
    lds_barrier();

    int* outb = out + (size_t)b * LL;
    for (int t = tid; t < LL; t += FNTH)
        outb[t] = (t < lenb) ? (int)sm.tags[t] : 0;
}

extern "C" void kernel_launch(void* const* d_in, const int* in_sizes, int n_in,
                              void* d_out, int out_size, void* d_ws, size_t ws_size,
                              hipStream_t stream) {
    const float* x       = (const float*)d_in[0];
    const int*   lengths = (const int*)d_in[1];
    // d_in[2] = tags (unused by decode)
    const float* trans   = (const float*)d_in[3];
    int*         out     = (int*)d_out;

    const size_t ws_needed = (size_t)BB * LL * TT * sizeof(float);  // 134 MB

    if (d_ws != nullptr && ws_size >= ws_needed) {
        // tT (padded, 64.5 KB) + bm/bx staging (64 KB) dynamic; ~3.7 KB static
        const int dyn = (TTP * TT + 2 * CH * TT) * (int)sizeof(float);  // 131584
        hipFuncSetAttribute((const void*)&viterbi_ws_kernel,
                            hipFuncAttributeMaxDynamicSharedMemorySize, dyn);
        viterbi_ws_kernel<<<BB, NTH, dyn, stream>>>(x, lengths, trans, out,
                                                    (float*)d_ws);
    } else {
        const int dyn = LL * TT;  // 131072 bytes of backpointers
        hipFuncSetAttribute((const void*)&viterbi_kernel,
                            hipFuncAttributeMaxDynamicSharedMemorySize, dyn);
        viterbi_kernel<<<BB, FNTH, dyn, stream>>>(x, lengths, trans, out);
    }
}